// Round 3
// baseline (506.275 us; speedup 1.0000x reference)
//
#include <hip/hip_runtime.h>
#include <hip/hip_bf16.h>
#include <hip/hip_fp16.h>

#define SEQ    2048
#define DMODEL 2048
#define NH     16
#define NKV    4
#define HD     128
#define NTOT   3072   // DMODEL + 2*NKV*HD
#define MROWS  4096   // B*SEQ

typedef __attribute__((ext_vector_type(4))) float f32x4;
typedef __attribute__((ext_vector_type(8))) __bf16 bf16x8;
typedef __attribute__((ext_vector_type(8))) unsigned short u16x8;
typedef __attribute__((ext_vector_type(4))) unsigned short u16x4;

__device__ __forceinline__ void async_copy16(const void* g, void* l) {
  __builtin_amdgcn_global_load_lds(
      (const __attribute__((address_space(1))) void*)g,
      (__attribute__((address_space(3))) void*)l, 16, 0, 0);
}

__device__ __forceinline__ unsigned short fto16(float f) {
  __hip_bfloat16 h = __float2bfloat16(f);
  return *(unsigned short*)&h;
}

// ---------------- fake-quant (all 4 weights in one launch) ----------------
__global__ __launch_bounds__(256) void fq_kernel(const float* __restrict__ Wq,
                                                 const float* __restrict__ Wk,
                                                 const float* __restrict__ Wv,
                                                 const float* __restrict__ Wp,
                                                 unsigned short* __restrict__ Wcat,
                                                 unsigned short* __restrict__ Wpq) {
  int g = blockIdx.x * 4 + (threadIdx.x >> 6);
  int lane = threadIdx.x & 63;
  const float* W;
  unsigned short* out;
  int blk;
  if (g < 32768)      { W = Wq; out = Wcat;                          blk = g; }
  else if (g < 40960) { W = Wk; out = Wcat + (size_t)2048 * 2048;    blk = g - 32768; }
  else if (g < 49152) { W = Wv; out = Wcat + (size_t)2560 * 2048;    blk = g - 40960; }
  else                { W = Wp; out = Wpq;                           blk = g - 49152; }
  const float* p = W + (size_t)blk * 128 + lane * 2;
  float w0 = p[0], w1 = p[1];
  float m = fmaxf(fabsf(w0), fabsf(w1));
#pragma unroll
  for (int o = 32; o; o >>= 1) m = fmaxf(m, __shfl_xor(m, o));
  float s = fmaxf(m / 31.0f, 1e-12f);
  s = __half2float(__float2half(s));        // fp16 RNE round of scale
  s = fmaxf(s, 6.103515625e-05f);           // fp16 tiny
  float q0 = rintf(fminf(fmaxf(w0 / s, -32.0f), 31.0f)) * s;
  float q1 = rintf(fminf(fmaxf(w1 / s, -32.0f), 31.0f)) * s;
  unsigned short* o16 = out + (size_t)blk * 128 + lane * 2;
  o16[0] = fto16(q0);
  o16[1] = fto16(q1);
}

// ---------------- fp32 -> bf16 convert ----------------
__global__ __launch_bounds__(256) void conv_kernel(const float* __restrict__ in,
                                                   unsigned short* __restrict__ out,
                                                   int n) {
  int i = (blockIdx.x * blockDim.x + threadIdx.x) * 4;
  if (i >= n) return;
  float4 v = *(const float4*)(in + i);
  ushort4 o;
  o.x = fto16(v.x); o.y = fto16(v.y); o.z = fto16(v.z); o.w = fto16(v.w);
  *(ushort4*)(out + i) = o;
}

// ---------------- bf16 MFMA GEMM, C[m,n] = sum_k A[m,k]*B[n,k] ----------------
#define BM 128
#define BN 128
#define BK 32
__global__ __launch_bounds__(256) void gemm_bt(const unsigned short* __restrict__ A,
                                               const unsigned short* __restrict__ Bm,
                                               float* __restrict__ C,
                                               int M, int N, int K) {
  __shared__ unsigned short As[BM * BK];
  __shared__ unsigned short Bs[BN * BK];
  const int tid = threadIdx.x;
  const int wave = tid >> 6, lane = tid & 63;
  const int quad = lane >> 4, l16 = lane & 15;
  const int m0 = blockIdx.x * BM, n0 = blockIdx.y * BN;
  const int wm = (wave >> 1) * 64, wn = (wave & 1) * 64;
  const int sr = lane >> 2, sc = (lane & 3) * 8;

  const unsigned short* Ag = A + (size_t)m0 * K;
  const unsigned short* Bg = Bm + (size_t)n0 * K;

  f32x4 acc[4][4];
#pragma unroll
  for (int i = 0; i < 4; i++)
#pragma unroll
    for (int j = 0; j < 4; j++) acc[i][j] = f32x4{0.f, 0.f, 0.f, 0.f};

  const int seg0 = wave * 2, seg1 = wave * 2 + 1;
  unsigned short* lA0 = &As[seg0 * 16 * BK];
  unsigned short* lA1 = &As[seg1 * 16 * BK];
  unsigned short* lB0 = &Bs[seg0 * 16 * BK];
  unsigned short* lB1 = &Bs[seg1 * 16 * BK];
  const unsigned short* gA0 = Ag + (size_t)(seg0 * 16 + sr) * K + sc;
  const unsigned short* gA1 = Ag + (size_t)(seg1 * 16 + sr) * K + sc;
  const unsigned short* gB0 = Bg + (size_t)(seg0 * 16 + sr) * K + sc;
  const unsigned short* gB1 = Bg + (size_t)(seg1 * 16 + sr) * K + sc;

  for (int k0 = 0; k0 < K; k0 += BK) {
    __syncthreads();
    async_copy16(gA0 + k0, lA0);
    async_copy16(gA1 + k0, lA1);
    async_copy16(gB0 + k0, lB0);
    async_copy16(gB1 + k0, lB1);
    __syncthreads();
    bf16x8 af[4], bf[4];
#pragma unroll
    for (int t = 0; t < 4; t++)
      af[t] = *(const bf16x8*)&As[(wm + t * 16 + l16) * BK + quad * 8];
#pragma unroll
    for (int t = 0; t < 4; t++)
      bf[t] = *(const bf16x8*)&Bs[(wn + t * 16 + l16) * BK + quad * 8];
#pragma unroll
    for (int i = 0; i < 4; i++)
#pragma unroll
      for (int j = 0; j < 4; j++)
        acc[i][j] = __builtin_amdgcn_mfma_f32_16x16x32_bf16(af[i], bf[j], acc[i][j], 0, 0, 0);
  }
#pragma unroll
  for (int i = 0; i < 4; i++) {
    int row_base = m0 + wm + i * 16 + quad * 4;
#pragma unroll
    for (int j = 0; j < 4; j++) {
      int col = n0 + wn + j * 16 + l16;
#pragma unroll
      for (int r = 0; r < 4; r++)
        C[(size_t)(row_base + r) * N + col] = acc[i][j][r];
    }
  }
}

// ---------------- RMSNorm + RoPE + gain (Q,K only), bf16 emit in (b,h,s,d) ----------------
// Q additionally folds in softmax scale (1/sqrt(hd)) * log2(e) so attention
// can use exp2 directly with no per-element multiply.
#define QSCALE 0.12751791437524245f   // (1/sqrt(128)) * log2(e)
__global__ __launch_bounds__(256) void normrope_kernel(const float* __restrict__ qkv,
                                                       const float* __restrict__ qgain,
                                                       unsigned short* __restrict__ qbuf,
                                                       unsigned short* __restrict__ kbuf) {
  const int i = blockIdx.x;            // token 0..4095
  const int bz = i >> 11, tok = i & 2047;
  const int wave = threadIdx.x >> 6, lane = threadIdx.x & 63;
  const float* row = qkv + (size_t)i * NTOT;

  double invf = pow(10000.0, -(double)(2 * lane) / 128.0);
  float freq = (float)((double)tok * invf);
  float cs = cosf(freq), sn = sinf(freq);

  for (int slot = wave; slot < 20; slot += 4) {
    if (slot < 16) {                   // q heads: norm + rope + gain*scale
      int hh = slot;
      const float* src = row + hh * HD;
      float x1 = src[lane], x2 = src[lane + 64];
      float ss = x1 * x1 + x2 * x2;
#pragma unroll
      for (int o = 32; o; o >>= 1) ss += __shfl_xor(ss, o);
      float rn = rsqrtf(ss * (1.0f / 128.0f) + 1.1920929e-07f);
      float n1 = x1 * rn, n2 = x2 * rn;
      float g = qgain[hh] * QSCALE;
      unsigned short* dst = qbuf + ((size_t)(bz * NH + hh) * SEQ + tok) * HD;
      dst[lane]      = fto16((n1 * cs + n2 * sn) * g);
      dst[lane + 64] = fto16((-n1 * sn + n2 * cs) * g);
    } else {                           // k heads: norm + rope
      int hh = slot - 16;
      const float* src = row + DMODEL + hh * HD;
      float x1 = src[lane], x2 = src[lane + 64];
      float ss = x1 * x1 + x2 * x2;
#pragma unroll
      for (int o = 32; o; o >>= 1) ss += __shfl_xor(ss, o);
      float rn = rsqrtf(ss * (1.0f / 128.0f) + 1.1920929e-07f);
      float n1 = x1 * rn, n2 = x2 * rn;
      unsigned short* dst = kbuf + ((size_t)(bz * NKV + hh) * SEQ + tok) * HD;
      dst[lane]      = fto16(n1 * cs + n2 * sn);
      dst[lane + 64] = fto16(-n1 * sn + n2 * cs);
    }
  }
}

// ---------------- V transpose: qkv fp32 v-section -> bf16 V^T [b,kvh,d,s] ----------------
__global__ __launch_bounds__(256) void vtrans_kernel(const float* __restrict__ qkv,
                                                     unsigned short* __restrict__ vtb) {
  __shared__ unsigned short T[64 * 72];
  const int s0 = blockIdx.x * 64;
  const int d0 = blockIdx.y * 64;
  const int bz = blockIdx.z >> 2, h = blockIdx.z & 3;
  const int tid = threadIdx.x;
#pragma unroll
  for (int i = 0; i < 2; ++i) {
    int c = i * 256 + tid;
    int s = c >> 3, ch = c & 7;
    const float* src = qkv + (size_t)(bz * SEQ + s0 + s) * NTOT + DMODEL + 512 + h * HD + d0 + ch * 8;
    float4 a = *(const float4*)src;
    float4 b = *(const float4*)(src + 4);
    u16x8 v;
    v[0] = fto16(a.x); v[1] = fto16(a.y); v[2] = fto16(a.z); v[3] = fto16(a.w);
    v[4] = fto16(b.x); v[5] = fto16(b.y); v[6] = fto16(b.z); v[7] = fto16(b.w);
    *(u16x8*)&T[s * 72 + ch * 8] = v;
  }
  __syncthreads();
  unsigned short* outg = vtb + (size_t)(bz * NKV + h) * HD * SEQ;
#pragma unroll
  for (int i = 0; i < 2; ++i) {
    int c = i * 256 + tid;
    int d = c >> 3, sc = c & 7;
    u16x8 v;
#pragma unroll
    for (int j = 0; j < 8; ++j) v[j] = T[(sc * 8 + j) * 72 + d];
    *(u16x8*)(outg + (size_t)(d0 + d) * SEQ + s0 + sc * 8) = v;
  }
}

// ---------------- flash attention: barrier-free, K/V fragments from global ----------------
#define PS_ST 72
__global__ __launch_bounds__(256) void attn_kernel(const unsigned short* __restrict__ qb,
                                                   const unsigned short* __restrict__ kb,
                                                   const unsigned short* __restrict__ vtb,
                                                   unsigned short* __restrict__ yb) {
  __shared__ unsigned short Ps[4][16 * PS_ST];   // per-wave P [row16][kpos64]

  const int pair = blockIdx.x;   // 0..15 -> qtiles {pair, 31-pair}
  const int h = blockIdx.y;
  const int bz = blockIdx.z;
  const int tid = threadIdx.x;
  const int wave = tid >> 6, lane = tid & 63;
  const int quad = lane >> 4, l16 = lane & 15;

  const unsigned short* qg = qb + (size_t)(bz * NH + h) * SEQ * HD;
  const unsigned short* kg = kb + (size_t)(bz * NKV + (h >> 2)) * SEQ * HD;
  const unsigned short* vg = vtb + (size_t)(bz * NKV + (h >> 2)) * HD * SEQ;

  const int qts[2] = {pair, 31 - pair};

  for (int ti = 0; ti < 2; ++ti) {
    const int qt = qts[ti];
    const int q0 = qt * 64;
    const int qrow = q0 + wave * 16 + l16;     // softmax row owned by this lane

    bf16x8 qf[4];
#pragma unroll
    for (int ds = 0; ds < 4; ++ds)
      qf[ds] = *(const bf16x8*)(qg + (size_t)qrow * HD + ds * 32 + quad * 8);

    f32x4 oacc[8];
#pragma unroll
    for (int j = 0; j < 8; ++j) oacc[j] = f32x4{0.f, 0.f, 0.f, 0.f};
    float m_i = -__builtin_inff(), l_i = 0.f;

    for (int kt = 0; kt <= qt; ++kt) {
      // S^T = K * Q^T ; K fragments straight from global (L1/L2-cached)
      f32x4 st[4];
#pragma unroll
      for (int mt = 0; mt < 4; ++mt) {
        st[mt] = f32x4{0.f, 0.f, 0.f, 0.f};
#pragma unroll
        for (int ds = 0; ds < 4; ++ds) {
          bf16x8 kf = *(const bf16x8*)(kg + (size_t)(kt * 64 + mt * 16 + l16) * HD + ds * 32 + quad * 8);
          st[mt] = __builtin_amdgcn_mfma_f32_16x16x32_bf16(kf, qf[ds], st[mt], 0, 0, 0);
        }
      }

      // V^T fragments from global; issued before softmax so loads overlap VALU
      bf16x8 vf[16];
#pragma unroll
      for (int c = 0; c < 2; ++c)
#pragma unroll
        for (int j = 0; j < 8; ++j)
          vf[c * 8 + j] = *(const bf16x8*)(vg + (size_t)(j * 16 + l16) * SEQ + kt * 64 + c * 32 + quad * 8);

      // online softmax in exp2 domain (scale*log2e folded into q)
      float p[4][4];
      float mx = -__builtin_inff();
      if (kt == qt) {                    // diagonal tile: apply causal mask
#pragma unroll
        for (int mt = 0; mt < 4; ++mt)
#pragma unroll
          for (int r = 0; r < 4; ++r) {
            int kp = kt * 64 + mt * 16 + quad * 4 + r;
            float v = (kp <= qrow) ? st[mt][r] : -__builtin_inff();
            p[mt][r] = v;
            mx = fmaxf(mx, v);
          }
      } else {
#pragma unroll
        for (int mt = 0; mt < 4; ++mt)
#pragma unroll
          for (int r = 0; r < 4; ++r) {
            p[mt][r] = st[mt][r];
            mx = fmaxf(mx, st[mt][r]);
          }
      }
      mx = fmaxf(mx, __shfl_xor(mx, 16));
      mx = fmaxf(mx, __shfl_xor(mx, 32));
      float mnew = fmaxf(m_i, mx);
      float a = exp2f(m_i - mnew);
      float rs = 0.f;
#pragma unroll
      for (int mt = 0; mt < 4; ++mt)
#pragma unroll
        for (int r = 0; r < 4; ++r) {
          float e = exp2f(p[mt][r] - mnew);
          p[mt][r] = e;
          rs += e;
        }
      rs += __shfl_xor(rs, 16);
      rs += __shfl_xor(rs, 32);
      l_i = l_i * a + rs;
      m_i = mnew;

      // P store (vectorized, per-wave buffer, no barrier needed)
#pragma unroll
      for (int mt = 0; mt < 4; ++mt) {
        u16x4 pk;
#pragma unroll
        for (int r = 0; r < 4; ++r) pk[r] = fto16(p[mt][r]);
        *(u16x4*)&Ps[wave][l16 * PS_ST + mt * 16 + quad * 4] = pk;
      }

      // broadcast alpha to C-layout rows, rescale O
      float ar[4];
#pragma unroll
      for (int r = 0; r < 4; ++r) ar[r] = __shfl(a, quad * 4 + r);
#pragma unroll
      for (int j = 0; j < 8; ++j)
#pragma unroll
        for (int r = 0; r < 4; ++r) oacc[j][r] *= ar[r];

      __asm__ volatile("s_waitcnt lgkmcnt(0)" ::: "memory");  // P writes -> own reads

      // O += P * V
#pragma unroll
      for (int c = 0; c < 2; ++c) {
        bf16x8 pf = *(const bf16x8*)&Ps[wave][l16 * PS_ST + c * 32 + quad * 8];
#pragma unroll
        for (int j = 0; j < 8; ++j)
          oacc[j] = __builtin_amdgcn_mfma_f32_16x16x32_bf16(pf, vf[c * 8 + j], oacc[j], 0, 0, 0);
      }
    }

    // epilogue
    float il = 1.0f / l_i;
    float ilr[4];
#pragma unroll
    for (int r = 0; r < 4; ++r) ilr[r] = __shfl(il, quad * 4 + r);
#pragma unroll
    for (int j = 0; j < 8; ++j)
#pragma unroll
      for (int r = 0; r < 4; ++r) {
        int rowg = q0 + wave * 16 + quad * 4 + r;
        yb[(size_t)(bz * SEQ + rowg) * DMODEL + h * HD + j * 16 + l16] =
            fto16(oacc[j][r] * ilr[r]);
      }
  }
}

extern "C" void kernel_launch(void* const* d_in, const int* in_sizes, int n_in,
                              void* d_out, int out_size, void* d_ws, size_t ws_size,
                              hipStream_t stream) {
  (void)in_sizes; (void)n_in; (void)out_size; (void)ws_size;
  const float* x  = (const float*)d_in[0];
  const float* Wq = (const float*)d_in[1];
  const float* Wk = (const float*)d_in[2];
  const float* Wv = (const float*)d_in[3];
  const float* Wp = (const float*)d_in[4];
  const float* qg = (const float*)d_in[5];
  float* out = (float*)d_out;
  char* ws = (char*)d_ws;

  // workspace layout; yb aliases xb (x consumed by GEMM1 before attn writes y)
  unsigned short* xb   = (unsigned short*)(ws + 0);          // 16.78 MB
  unsigned short* Wcat = (unsigned short*)(ws + 16777216);   // 12.58 MB (Wq|Wk|Wv rows)
  unsigned short* Wpq  = (unsigned short*)(ws + 29360128);   // 8.39 MB
  float*          qkv  = (float*)(ws + 37748736);            // 50.33 MB
  unsigned short* qbuf = (unsigned short*)(ws + 88080384);   // 16.78 MB
  unsigned short* kbuf = (unsigned short*)(ws + 104857600);  // 4.19 MB
  unsigned short* vtb  = (unsigned short*)(ws + 109051904);  // 4.19 MB (V^T)
  unsigned short* yb   = xb;

  fq_kernel<<<81920 / 4, 256, 0, stream>>>(Wq, Wk, Wv, Wp, Wcat, Wpq);
  conv_kernel<<<8388608 / 1024, 256, 0, stream>>>(x, xb, 8388608);
  gemm_bt<<<dim3(32, 24), 256, 0, stream>>>(xb, Wcat, qkv, MROWS, NTOT, DMODEL);
  normrope_kernel<<<MROWS, 256, 0, stream>>>(qkv, qg, qbuf, kbuf);
  vtrans_kernel<<<dim3(32, 2, 8), 256, 0, stream>>>(qkv, vtb);
  attn_kernel<<<dim3(16, NH, 2), 256, 0, stream>>>(qbuf, kbuf, vtb, yb);
  gemm_bt<<<dim3(32, 16), 256, 0, stream>>>(yb, Wpq, out, MROWS, DMODEL, DMODEL);
}

// Round 4
// 397.892 us; speedup vs baseline: 1.2724x; 1.2724x over previous
//
#include <hip/hip_runtime.h>
#include <hip/hip_bf16.h>
#include <hip/hip_fp16.h>

#define SEQ    2048
#define DMODEL 2048
#define NH     16
#define NKV    4
#define HD     128
#define NTOT   3072   // DMODEL + 2*NKV*HD
#define MROWS  4096   // B*SEQ

typedef __attribute__((ext_vector_type(4))) float f32x4;
typedef __attribute__((ext_vector_type(8))) __bf16 bf16x8;
typedef __attribute__((ext_vector_type(8))) unsigned short u16x8;
typedef __attribute__((ext_vector_type(4))) unsigned short u16x4;

__device__ __forceinline__ void async_copy16(const void* g, void* l) {
  __builtin_amdgcn_global_load_lds(
      (const __attribute__((address_space(1))) void*)g,
      (__attribute__((address_space(3))) void*)l, 16, 0, 0);
}

__device__ __forceinline__ unsigned short fto16(float f) {
  __hip_bfloat16 h = __float2bfloat16(f);
  return *(unsigned short*)&h;
}

__device__ __forceinline__ float b2f(unsigned short u) {
  unsigned int t = (unsigned int)u << 16;
  float f;
  __builtin_memcpy(&f, &t, 4);
  return f;
}

// ---------------- fake-quant (all 4 weights in one launch) ----------------
__global__ __launch_bounds__(256) void fq_kernel(const float* __restrict__ Wq,
                                                 const float* __restrict__ Wk,
                                                 const float* __restrict__ Wv,
                                                 const float* __restrict__ Wp,
                                                 unsigned short* __restrict__ Wcat,
                                                 unsigned short* __restrict__ Wpq) {
  int g = blockIdx.x * 4 + (threadIdx.x >> 6);
  int lane = threadIdx.x & 63;
  const float* W;
  unsigned short* out;
  int blk;
  if (g < 32768)      { W = Wq; out = Wcat;                          blk = g; }
  else if (g < 40960) { W = Wk; out = Wcat + (size_t)2048 * 2048;    blk = g - 32768; }
  else if (g < 49152) { W = Wv; out = Wcat + (size_t)2560 * 2048;    blk = g - 40960; }
  else                { W = Wp; out = Wpq;                           blk = g - 49152; }
  const float* p = W + (size_t)blk * 128 + lane * 2;
  float w0 = p[0], w1 = p[1];
  float m = fmaxf(fabsf(w0), fabsf(w1));
#pragma unroll
  for (int o = 32; o; o >>= 1) m = fmaxf(m, __shfl_xor(m, o));
  float s = fmaxf(m / 31.0f, 1e-12f);
  s = __half2float(__float2half(s));        // fp16 RNE round of scale
  s = fmaxf(s, 6.103515625e-05f);           // fp16 tiny
  float q0 = rintf(fminf(fmaxf(w0 / s, -32.0f), 31.0f)) * s;
  float q1 = rintf(fminf(fmaxf(w1 / s, -32.0f), 31.0f)) * s;
  unsigned short* o16 = out + (size_t)blk * 128 + lane * 2;
  o16[0] = fto16(q0);
  o16[1] = fto16(q1);
}

// ---------------- fp32 -> bf16 convert ----------------
__global__ __launch_bounds__(256) void conv_kernel(const float* __restrict__ in,
                                                   unsigned short* __restrict__ out,
                                                   int n) {
  int i = (blockIdx.x * blockDim.x + threadIdx.x) * 4;
  if (i >= n) return;
  float4 v = *(const float4*)(in + i);
  ushort4 o;
  o.x = fto16(v.x); o.y = fto16(v.y); o.z = fto16(v.z); o.w = fto16(v.w);
  *(ushort4*)(out + i) = o;
}

// ---------------- bf16 MFMA GEMM, C[m,n] = sum_k A[m,k]*B[n,k] ----------------
// OT = float (fp32 C) or unsigned short (bf16 C)
#define BM 128
#define BN 128
#define BK 32
template <typename OT>
__global__ __launch_bounds__(256) void gemm_bt(const unsigned short* __restrict__ A,
                                               const unsigned short* __restrict__ Bm,
                                               OT* __restrict__ C,
                                               int M, int N, int K) {
  __shared__ unsigned short As[BM * BK];
  __shared__ unsigned short Bs[BN * BK];
  const int tid = threadIdx.x;
  const int wave = tid >> 6, lane = tid & 63;
  const int quad = lane >> 4, l16 = lane & 15;
  const int m0 = blockIdx.x * BM, n0 = blockIdx.y * BN;
  const int wm = (wave >> 1) * 64, wn = (wave & 1) * 64;
  const int sr = lane >> 2, sc = (lane & 3) * 8;

  const unsigned short* Ag = A + (size_t)m0 * K;
  const unsigned short* Bg = Bm + (size_t)n0 * K;

  f32x4 acc[4][4];
#pragma unroll
  for (int i = 0; i < 4; i++)
#pragma unroll
    for (int j = 0; j < 4; j++) acc[i][j] = f32x4{0.f, 0.f, 0.f, 0.f};

  const int seg0 = wave * 2, seg1 = wave * 2 + 1;
  unsigned short* lA0 = &As[seg0 * 16 * BK];
  unsigned short* lA1 = &As[seg1 * 16 * BK];
  unsigned short* lB0 = &Bs[seg0 * 16 * BK];
  unsigned short* lB1 = &Bs[seg1 * 16 * BK];
  const unsigned short* gA0 = Ag + (size_t)(seg0 * 16 + sr) * K + sc;
  const unsigned short* gA1 = Ag + (size_t)(seg1 * 16 + sr) * K + sc;
  const unsigned short* gB0 = Bg + (size_t)(seg0 * 16 + sr) * K + sc;
  const unsigned short* gB1 = Bg + (size_t)(seg1 * 16 + sr) * K + sc;

  for (int k0 = 0; k0 < K; k0 += BK) {
    __syncthreads();
    async_copy16(gA0 + k0, lA0);
    async_copy16(gA1 + k0, lA1);
    async_copy16(gB0 + k0, lB0);
    async_copy16(gB1 + k0, lB1);
    __syncthreads();
    bf16x8 af[4], bf[4];
#pragma unroll
    for (int t = 0; t < 4; t++)
      af[t] = *(const bf16x8*)&As[(wm + t * 16 + l16) * BK + quad * 8];
#pragma unroll
    for (int t = 0; t < 4; t++)
      bf[t] = *(const bf16x8*)&Bs[(wn + t * 16 + l16) * BK + quad * 8];
#pragma unroll
    for (int i = 0; i < 4; i++)
#pragma unroll
      for (int j = 0; j < 4; j++)
        acc[i][j] = __builtin_amdgcn_mfma_f32_16x16x32_bf16(af[i], bf[j], acc[i][j], 0, 0, 0);
  }
#pragma unroll
  for (int i = 0; i < 4; i++) {
    int row_base = m0 + wm + i * 16 + quad * 4;
#pragma unroll
    for (int j = 0; j < 4; j++) {
      int col = n0 + wn + j * 16 + l16;
#pragma unroll
      for (int r = 0; r < 4; r++) {
        if constexpr (sizeof(OT) == 2)
          C[(size_t)(row_base + r) * N + col] = fto16(acc[i][j][r]);
        else
          C[(size_t)(row_base + r) * N + col] = acc[i][j][r];
      }
    }
  }
}

// ---------------- RMSNorm + RoPE + gain (Q,K only), bf16 in/out ----------------
#define QSCALE 0.12751791437524245f   // (1/sqrt(128)) * log2(e)
__global__ __launch_bounds__(256) void normrope_kernel(const unsigned short* __restrict__ qkvb,
                                                       const float* __restrict__ qgain,
                                                       unsigned short* __restrict__ qbuf,
                                                       unsigned short* __restrict__ kbuf) {
  const int i = blockIdx.x;            // token 0..4095
  const int bz = i >> 11, tok = i & 2047;
  const int wave = threadIdx.x >> 6, lane = threadIdx.x & 63;
  const unsigned short* row = qkvb + (size_t)i * NTOT;

  double invf = pow(10000.0, -(double)(2 * lane) / 128.0);
  float freq = (float)((double)tok * invf);
  float cs = cosf(freq), sn = sinf(freq);

  for (int slot = wave; slot < 20; slot += 4) {
    if (slot < 16) {                   // q heads: norm + rope + gain*scale
      int hh = slot;
      const unsigned short* src = row + hh * HD;
      float x1 = b2f(src[lane]), x2 = b2f(src[lane + 64]);
      float ss = x1 * x1 + x2 * x2;
#pragma unroll
      for (int o = 32; o; o >>= 1) ss += __shfl_xor(ss, o);
      float rn = rsqrtf(ss * (1.0f / 128.0f) + 1.1920929e-07f);
      float n1 = x1 * rn, n2 = x2 * rn;
      float g = qgain[hh] * QSCALE;
      unsigned short* dst = qbuf + ((size_t)(bz * NH + hh) * SEQ + tok) * HD;
      dst[lane]      = fto16((n1 * cs + n2 * sn) * g);
      dst[lane + 64] = fto16((-n1 * sn + n2 * cs) * g);
    } else {                           // k heads: norm + rope
      int hh = slot - 16;
      const unsigned short* src = row + DMODEL + hh * HD;
      float x1 = b2f(src[lane]), x2 = b2f(src[lane + 64]);
      float ss = x1 * x1 + x2 * x2;
#pragma unroll
      for (int o = 32; o; o >>= 1) ss += __shfl_xor(ss, o);
      float rn = rsqrtf(ss * (1.0f / 128.0f) + 1.1920929e-07f);
      float n1 = x1 * rn, n2 = x2 * rn;
      unsigned short* dst = kbuf + ((size_t)(bz * NKV + hh) * SEQ + tok) * HD;
      dst[lane]      = fto16(n1 * cs + n2 * sn);
      dst[lane + 64] = fto16(-n1 * sn + n2 * cs);
    }
  }
}

// ---------------- V transpose: bf16 qkv v-section -> bf16 V^T [b,kvh,d,s] ----------------
__global__ __launch_bounds__(256) void vtrans_kernel(const unsigned short* __restrict__ qkvb,
                                                     unsigned short* __restrict__ vtb) {
  __shared__ unsigned short T[64 * 72];
  const int s0 = blockIdx.x * 64;
  const int d0 = blockIdx.y * 64;
  const int bz = blockIdx.z >> 2, h = blockIdx.z & 3;
  const int tid = threadIdx.x;
#pragma unroll
  for (int i = 0; i < 2; ++i) {
    int c = i * 256 + tid;
    int s = c >> 3, ch = c & 7;
    const unsigned short* src =
        qkvb + (size_t)(bz * SEQ + s0 + s) * NTOT + DMODEL + 512 + h * HD + d0 + ch * 8;
    *(u16x8*)&T[s * 72 + ch * 8] = *(const u16x8*)src;
  }
  __syncthreads();
  unsigned short* outg = vtb + (size_t)(bz * NKV + h) * HD * SEQ;
#pragma unroll
  for (int i = 0; i < 2; ++i) {
    int c = i * 256 + tid;
    int d = c >> 3, sc = c & 7;
    u16x8 v;
#pragma unroll
    for (int j = 0; j < 8; ++j) v[j] = T[(sc * 8 + j) * 72 + d];
    *(u16x8*)(outg + (size_t)(d0 + d) * SEQ + s0 + sc * 8) = v;
  }
}

// ---------------- flash attention: O^T formulation, reg-prefetched staging ----------------
#define KS_ST 136
#define VT_ST 72
#define PS_ST 72
__global__ __launch_bounds__(256, 3) void attn_kernel(const unsigned short* __restrict__ qb,
                                                      const unsigned short* __restrict__ kb,
                                                      const unsigned short* __restrict__ vtb,
                                                      unsigned short* __restrict__ yb) {
  __shared__ unsigned short Ks[64 * KS_ST];      // [kpos][d]
  __shared__ unsigned short Vt[HD * VT_ST];      // [d][kpos]
  __shared__ unsigned short Ps[4][16 * PS_ST];   // per-wave P [q16][kpos64]

  const int qt = 31 - blockIdx.x;     // big tiles dispatch first
  const int h = blockIdx.y;
  const int bz = blockIdx.z;
  const int tid = threadIdx.x;
  const int wave = tid >> 6, lane = tid & 63;
  const int quad = lane >> 4, l16 = lane & 15;
  const int q0 = qt * 64;
  const int qrow = q0 + wave * 16 + l16;   // this lane's softmax row

  const unsigned short* qg = qb + (size_t)(bz * NH + h) * SEQ * HD;
  const unsigned short* kg = kb + (size_t)(bz * NKV + (h >> 2)) * SEQ * HD;
  const unsigned short* vg = vtb + (size_t)(bz * NKV + (h >> 2)) * HD * SEQ;

  bf16x8 qf[4];
#pragma unroll
  for (int ds = 0; ds < 4; ++ds)
    qf[ds] = *(const bf16x8*)(qg + (size_t)qrow * HD + ds * 32 + quad * 8);

  f32x4 oacc[8];                       // O^T C-layout: row=d, col=q(=l16)
#pragma unroll
  for (int j = 0; j < 8; ++j) oacc[j] = f32x4{0.f, 0.f, 0.f, 0.f};
  float m_i = -__builtin_inff(), l_i = 0.f;

  // staging indices
  const int krw = tid >> 4, kch = (tid & 15) * 8;   // K: 16 rows per i-step
  const int vdw = tid >> 3, vch = (tid & 7) * 8;    // V: 32 d per i-step

  u16x8 pk[4], pv[4];
#pragma unroll
  for (int i = 0; i < 4; ++i)
    pk[i] = *(const u16x8*)(kg + (size_t)(i * 16 + krw) * HD + kch);
#pragma unroll
  for (int i = 0; i < 4; ++i)
    pv[i] = *(const u16x8*)(vg + (size_t)(i * 32 + vdw) * SEQ + vch);

  for (int kt = 0; kt <= qt; ++kt) {
#pragma unroll
    for (int i = 0; i < 4; ++i)
      *(u16x8*)&Ks[(i * 16 + krw) * KS_ST + kch] = pk[i];
#pragma unroll
    for (int i = 0; i < 4; ++i)
      *(u16x8*)&Vt[(i * 32 + vdw) * VT_ST + vch] = pv[i];
    __syncthreads();

    if (kt < qt) {                     // prefetch next tile (overlaps compute)
#pragma unroll
      for (int i = 0; i < 4; ++i)
        pk[i] = *(const u16x8*)(kg + (size_t)((kt + 1) * 64 + i * 16 + krw) * HD + kch);
#pragma unroll
      for (int i = 0; i < 4; ++i)
        pv[i] = *(const u16x8*)(vg + (size_t)(i * 32 + vdw) * SEQ + (kt + 1) * 64 + vch);
    }

    // S^T = K * Q^T  (A=K from LDS, B=Q from regs); C col = q = l16
    f32x4 st[4];
#pragma unroll
    for (int mt = 0; mt < 4; ++mt) {
      st[mt] = f32x4{0.f, 0.f, 0.f, 0.f};
#pragma unroll
      for (int ds = 0; ds < 4; ++ds) {
        bf16x8 kf = *(const bf16x8*)&Ks[(mt * 16 + l16) * KS_ST + ds * 32 + quad * 8];
        st[mt] = __builtin_amdgcn_mfma_f32_16x16x32_bf16(kf, qf[ds], st[mt], 0, 0, 0);
      }
    }

    // online softmax in exp2 domain; all state keyed by l16 (lane-local q-row)
    float p[4][4];
    float mx = -__builtin_inff();
    if (kt == qt) {                    // diagonal tile: causal mask
#pragma unroll
      for (int mt = 0; mt < 4; ++mt)
#pragma unroll
        for (int r = 0; r < 4; ++r) {
          int kp = kt * 64 + mt * 16 + quad * 4 + r;
          float v = (kp <= qrow) ? st[mt][r] : -__builtin_inff();
          p[mt][r] = v;
          mx = fmaxf(mx, v);
        }
    } else {
#pragma unroll
      for (int mt = 0; mt < 4; ++mt)
#pragma unroll
        for (int r = 0; r < 4; ++r) {
          p[mt][r] = st[mt][r];
          mx = fmaxf(mx, st[mt][r]);
        }
    }
    mx = fmaxf(mx, __shfl_xor(mx, 16));
    mx = fmaxf(mx, __shfl_xor(mx, 32));
    float mnew = fmaxf(m_i, mx);
    float a = exp2f(m_i - mnew);
    float rs = 0.f;
#pragma unroll
    for (int mt = 0; mt < 4; ++mt)
#pragma unroll
      for (int r = 0; r < 4; ++r) {
        float e = exp2f(p[mt][r] - mnew);
        p[mt][r] = e;
        rs += e;
      }
    rs += __shfl_xor(rs, 16);
    rs += __shfl_xor(rs, 32);
    l_i = l_i * a + rs;
    m_i = mnew;

    // P store [q=l16][kpos], vectorized
#pragma unroll
    for (int mt = 0; mt < 4; ++mt) {
      u16x4 pkv;
#pragma unroll
      for (int r = 0; r < 4; ++r) pkv[r] = fto16(p[mt][r]);
      *(u16x4*)&Ps[wave][l16 * PS_ST + mt * 16 + quad * 4] = pkv;
    }

    // rescale O^T by alpha — per-lane, no broadcast needed (col=q=l16)
#pragma unroll
    for (int j = 0; j < 8; ++j) oacc[j] *= a;

    __asm__ volatile("s_waitcnt lgkmcnt(0)" ::: "memory");  // P writes -> own reads

    // O^T += V^T * P^T : A = V^T[d][kpos] frag, B = P[q][kpos] frag
#pragma unroll
    for (int c = 0; c < 2; ++c) {
      bf16x8 pf = *(const bf16x8*)&Ps[wave][l16 * PS_ST + c * 32 + quad * 8];
#pragma unroll
      for (int mt = 0; mt < 8; ++mt) {
        bf16x8 vf = *(const bf16x8*)&Vt[(mt * 16 + l16) * VT_ST + c * 32 + quad * 8];
        oacc[mt] = __builtin_amdgcn_mfma_f32_16x16x32_bf16(vf, pf, oacc[mt], 0, 0, 0);
      }
    }
    __syncthreads();                   // all reads done before next tile's stores
  }

  // epilogue: O^T row=d=mt*16+quad*4+r, col=q=l16 — per-lane invl, contiguous d-runs
  float il = 1.0f / l_i;
#pragma unroll
  for (int mt = 0; mt < 8; ++mt) {
    u16x4 o;
#pragma unroll
    for (int r = 0; r < 4; ++r) o[r] = fto16(oacc[mt][r] * il);
    *(u16x4*)&yb[(size_t)(bz * SEQ + qrow) * DMODEL + h * HD + mt * 16 + quad * 4] = o;
  }
}

extern "C" void kernel_launch(void* const* d_in, const int* in_sizes, int n_in,
                              void* d_out, int out_size, void* d_ws, size_t ws_size,
                              hipStream_t stream) {
  (void)in_sizes; (void)n_in; (void)out_size; (void)ws_size;
  const float* x  = (const float*)d_in[0];
  const float* Wq = (const float*)d_in[1];
  const float* Wk = (const float*)d_in[2];
  const float* Wv = (const float*)d_in[3];
  const float* Wp = (const float*)d_in[4];
  const float* qg = (const float*)d_in[5];
  float* out = (float*)d_out;
  char* ws = (char*)d_ws;

  // workspace layout; yb aliases xb (x consumed by GEMM1 before attn writes y)
  unsigned short* xb   = (unsigned short*)(ws + 0);          // 16.78 MB
  unsigned short* Wcat = (unsigned short*)(ws + 16777216);   // 12.58 MB (Wq|Wk|Wv rows)
  unsigned short* Wpq  = (unsigned short*)(ws + 29360128);   // 8.39 MB
  unsigned short* qkvb = (unsigned short*)(ws + 37748736);   // 25.17 MB (bf16 qkv)
  unsigned short* qbuf = (unsigned short*)(ws + 62914560);   // 16.78 MB
  unsigned short* kbuf = (unsigned short*)(ws + 79691776);   // 4.19 MB
  unsigned short* vtb  = (unsigned short*)(ws + 83886080);   // 4.19 MB (V^T)
  unsigned short* yb   = xb;

  fq_kernel<<<81920 / 4, 256, 0, stream>>>(Wq, Wk, Wv, Wp, Wcat, Wpq);
  conv_kernel<<<8388608 / 1024, 256, 0, stream>>>(x, xb, 8388608);
  gemm_bt<unsigned short><<<dim3(32, 24), 256, 0, stream>>>(xb, Wcat, qkvb, MROWS, NTOT, DMODEL);
  normrope_kernel<<<MROWS, 256, 0, stream>>>(qkvb, qg, qbuf, kbuf);
  vtrans_kernel<<<dim3(32, 2, 8), 256, 0, stream>>>(qkvb, vtb);
  attn_kernel<<<dim3(32, NH, 2), 256, 0, stream>>>(qbuf, kbuf, vtb, yb);
  gemm_bt<float><<<dim3(32, 16), 256, 0, stream>>>(yb, Wpq, out, MROWS, DMODEL, DMODEL);
}

// Round 5
// 336.273 us; speedup vs baseline: 1.5055x; 1.1832x over previous
//
#include <hip/hip_runtime.h>
#include <hip/hip_bf16.h>
#include <hip/hip_fp16.h>

#define SEQ    2048
#define DMODEL 2048
#define NH     16
#define NKV    4
#define HD     128
#define NTOT   3072   // DMODEL + 2*NKV*HD
#define MROWS  4096   // B*SEQ

typedef __attribute__((ext_vector_type(4))) float f32x4;
typedef __attribute__((ext_vector_type(8))) __bf16 bf16x8;
typedef __attribute__((ext_vector_type(8))) unsigned short u16x8;
typedef __attribute__((ext_vector_type(4))) unsigned short u16x4;

__device__ __forceinline__ void async_copy16(const void* g, void* l) {
  __builtin_amdgcn_global_load_lds(
      (const __attribute__((address_space(1))) void*)g,
      (__attribute__((address_space(3))) void*)l, 16, 0, 0);
}

__device__ __forceinline__ unsigned short fto16(float f) {
  __hip_bfloat16 h = __float2bfloat16(f);
  return *(unsigned short*)&h;
}

__device__ __forceinline__ float b2f(unsigned short u) {
  unsigned int t = (unsigned int)u << 16;
  float f;
  __builtin_memcpy(&f, &t, 4);
  return f;
}

// ---------------- fake-quant (all 4 weights in one launch) ----------------
__global__ __launch_bounds__(256) void fq_kernel(const float* __restrict__ Wq,
                                                 const float* __restrict__ Wk,
                                                 const float* __restrict__ Wv,
                                                 const float* __restrict__ Wp,
                                                 unsigned short* __restrict__ Wcat,
                                                 unsigned short* __restrict__ Wpq) {
  int g = blockIdx.x * 4 + (threadIdx.x >> 6);
  int lane = threadIdx.x & 63;
  const float* W;
  unsigned short* out;
  int blk;
  if (g < 32768)      { W = Wq; out = Wcat;                          blk = g; }
  else if (g < 40960) { W = Wk; out = Wcat + (size_t)2048 * 2048;    blk = g - 32768; }
  else if (g < 49152) { W = Wv; out = Wcat + (size_t)2560 * 2048;    blk = g - 40960; }
  else                { W = Wp; out = Wpq;                           blk = g - 49152; }
  const float* p = W + (size_t)blk * 128 + lane * 2;
  float w0 = p[0], w1 = p[1];
  float m = fmaxf(fabsf(w0), fabsf(w1));
#pragma unroll
  for (int o = 32; o; o >>= 1) m = fmaxf(m, __shfl_xor(m, o));
  float s = fmaxf(m / 31.0f, 1e-12f);
  s = __half2float(__float2half(s));        // fp16 RNE round of scale
  s = fmaxf(s, 6.103515625e-05f);           // fp16 tiny
  float q0 = rintf(fminf(fmaxf(w0 / s, -32.0f), 31.0f)) * s;
  float q1 = rintf(fminf(fmaxf(w1 / s, -32.0f), 31.0f)) * s;
  unsigned short* o16 = out + (size_t)blk * 128 + lane * 2;
  o16[0] = fto16(q0);
  o16[1] = fto16(q1);
}

// ---------------- fp32 -> bf16 convert ----------------
__global__ __launch_bounds__(256) void conv_kernel(const float* __restrict__ in,
                                                   unsigned short* __restrict__ out,
                                                   int n) {
  int i = (blockIdx.x * blockDim.x + threadIdx.x) * 4;
  if (i >= n) return;
  float4 v = *(const float4*)(in + i);
  ushort4 o;
  o.x = fto16(v.x); o.y = fto16(v.y); o.z = fto16(v.z); o.w = fto16(v.w);
  *(ushort4*)(out + i) = o;
}

// ---------------- bf16 MFMA GEMM, C[m,n] = sum_k A[m,k]*B[n,k] ----------------
#define BM 128
#define BN 128
#define BK 32
template <typename OT>
__global__ __launch_bounds__(256) void gemm_bt(const unsigned short* __restrict__ A,
                                               const unsigned short* __restrict__ Bm,
                                               OT* __restrict__ C,
                                               int M, int N, int K) {
  __shared__ unsigned short As[BM * BK];
  __shared__ unsigned short Bs[BN * BK];
  const int tid = threadIdx.x;
  const int wave = tid >> 6, lane = tid & 63;
  const int quad = lane >> 4, l16 = lane & 15;
  const int m0 = blockIdx.x * BM, n0 = blockIdx.y * BN;
  const int wm = (wave >> 1) * 64, wn = (wave & 1) * 64;
  const int sr = lane >> 2, sc = (lane & 3) * 8;

  const unsigned short* Ag = A + (size_t)m0 * K;
  const unsigned short* Bg = Bm + (size_t)n0 * K;

  f32x4 acc[4][4];
#pragma unroll
  for (int i = 0; i < 4; i++)
#pragma unroll
    for (int j = 0; j < 4; j++) acc[i][j] = f32x4{0.f, 0.f, 0.f, 0.f};

  const int seg0 = wave * 2, seg1 = wave * 2 + 1;
  unsigned short* lA0 = &As[seg0 * 16 * BK];
  unsigned short* lA1 = &As[seg1 * 16 * BK];
  unsigned short* lB0 = &Bs[seg0 * 16 * BK];
  unsigned short* lB1 = &Bs[seg1 * 16 * BK];
  const unsigned short* gA0 = Ag + (size_t)(seg0 * 16 + sr) * K + sc;
  const unsigned short* gA1 = Ag + (size_t)(seg1 * 16 + sr) * K + sc;
  const unsigned short* gB0 = Bg + (size_t)(seg0 * 16 + sr) * K + sc;
  const unsigned short* gB1 = Bg + (size_t)(seg1 * 16 + sr) * K + sc;

  for (int k0 = 0; k0 < K; k0 += BK) {
    __syncthreads();
    async_copy16(gA0 + k0, lA0);
    async_copy16(gA1 + k0, lA1);
    async_copy16(gB0 + k0, lB0);
    async_copy16(gB1 + k0, lB1);
    __syncthreads();
    bf16x8 af[4], bf[4];
#pragma unroll
    for (int t = 0; t < 4; t++)
      af[t] = *(const bf16x8*)&As[(wm + t * 16 + l16) * BK + quad * 8];
#pragma unroll
    for (int t = 0; t < 4; t++)
      bf[t] = *(const bf16x8*)&Bs[(wn + t * 16 + l16) * BK + quad * 8];
#pragma unroll
    for (int i = 0; i < 4; i++)
#pragma unroll
      for (int j = 0; j < 4; j++)
        acc[i][j] = __builtin_amdgcn_mfma_f32_16x16x32_bf16(af[i], bf[j], acc[i][j], 0, 0, 0);
  }
#pragma unroll
  for (int i = 0; i < 4; i++) {
    int row_base = m0 + wm + i * 16 + quad * 4;
#pragma unroll
    for (int j = 0; j < 4; j++) {
      int col = n0 + wn + j * 16 + l16;
#pragma unroll
      for (int r = 0; r < 4; r++) {
        if constexpr (sizeof(OT) == 2)
          C[(size_t)(row_base + r) * N + col] = fto16(acc[i][j][r]);
        else
          C[(size_t)(row_base + r) * N + col] = acc[i][j][r];
      }
    }
  }
}

// ---------------- RMSNorm + RoPE + gain (Q,K only), bf16 in/out ----------------
#define QSCALE 0.12751791437524245f   // (1/sqrt(128)) * log2(e)
__global__ __launch_bounds__(256) void normrope_kernel(const unsigned short* __restrict__ qkvb,
                                                       const float* __restrict__ qgain,
                                                       unsigned short* __restrict__ qbuf,
                                                       unsigned short* __restrict__ kbuf) {
  const int i = blockIdx.x;            // token 0..4095
  const int bz = i >> 11, tok = i & 2047;
  const int wave = threadIdx.x >> 6, lane = threadIdx.x & 63;
  const unsigned short* row = qkvb + (size_t)i * NTOT;

  double invf = pow(10000.0, -(double)(2 * lane) / 128.0);
  float freq = (float)((double)tok * invf);
  float cs = cosf(freq), sn = sinf(freq);

  for (int slot = wave; slot < 20; slot += 4) {
    if (slot < 16) {                   // q heads: norm + rope + gain*scale
      int hh = slot;
      const unsigned short* src = row + hh * HD;
      float x1 = b2f(src[lane]), x2 = b2f(src[lane + 64]);
      float ss = x1 * x1 + x2 * x2;
#pragma unroll
      for (int o = 32; o; o >>= 1) ss += __shfl_xor(ss, o);
      float rn = rsqrtf(ss * (1.0f / 128.0f) + 1.1920929e-07f);
      float n1 = x1 * rn, n2 = x2 * rn;
      float g = qgain[hh] * QSCALE;
      unsigned short* dst = qbuf + ((size_t)(bz * NH + hh) * SEQ + tok) * HD;
      dst[lane]      = fto16((n1 * cs + n2 * sn) * g);
      dst[lane + 64] = fto16((-n1 * sn + n2 * cs) * g);
    } else {                           // k heads: norm + rope
      int hh = slot - 16;
      const unsigned short* src = row + DMODEL + hh * HD;
      float x1 = b2f(src[lane]), x2 = b2f(src[lane + 64]);
      float ss = x1 * x1 + x2 * x2;
#pragma unroll
      for (int o = 32; o; o >>= 1) ss += __shfl_xor(ss, o);
      float rn = rsqrtf(ss * (1.0f / 128.0f) + 1.1920929e-07f);
      float n1 = x1 * rn, n2 = x2 * rn;
      unsigned short* dst = kbuf + ((size_t)(bz * NKV + hh) * SEQ + tok) * HD;
      dst[lane]      = fto16(n1 * cs + n2 * sn);
      dst[lane + 64] = fto16(-n1 * sn + n2 * cs);
    }
  }
}

// ---------------- V transpose: bf16 qkv v-section -> bf16 V^T [b,kvh,d,s] ----------------
__global__ __launch_bounds__(256) void vtrans_kernel(const unsigned short* __restrict__ qkvb,
                                                     unsigned short* __restrict__ vtb) {
  __shared__ unsigned short T[64 * 72];
  const int s0 = blockIdx.x * 64;
  const int d0 = blockIdx.y * 64;
  const int bz = blockIdx.z >> 2, h = blockIdx.z & 3;
  const int tid = threadIdx.x;
#pragma unroll
  for (int i = 0; i < 2; ++i) {
    int c = i * 256 + tid;
    int s = c >> 3, ch = c & 7;
    const unsigned short* src =
        qkvb + (size_t)(bz * SEQ + s0 + s) * NTOT + DMODEL + 512 + h * HD + d0 + ch * 8;
    *(u16x8*)&T[s * 72 + ch * 8] = *(const u16x8*)src;
  }
  __syncthreads();
  unsigned short* outg = vtb + (size_t)(bz * NKV + h) * HD * SEQ;
#pragma unroll
  for (int i = 0; i < 2; ++i) {
    int c = i * 256 + tid;
    int d = c >> 3, sc = c & 7;
    u16x8 v;
#pragma unroll
    for (int j = 0; j < 8; ++j) v[j] = T[(sc * 8 + j) * 72 + d];
    *(u16x8*)(outg + (size_t)(d0 + d) * SEQ + s0 + sc * 8) = v;
  }
}

// ---------------- flash attention: 128-row Q tile, XOR-swizzled LDS, O^T form ----
// LDS layouts (flat strides are multiples of 32 dwords -> bank = f(granule only)):
//   Ks[row(kpos)][d]  : elem = row*128 + ((g ^ (row&15))<<3) + (d&7),  g = d>>3
//   Vt[d][kpos]       : elem = d*64   + ((g ^ (d&7))<<3)   + (kp&7),  g = kp>>3
//   Ps[wave][rq][kpos]: elem = rq*64  + ((g ^ (rq&7))<<3)  + (kp&7),  g = kp>>3
__global__ __launch_bounds__(256, 2) void attn_kernel(const unsigned short* __restrict__ qb,
                                                      const unsigned short* __restrict__ kb,
                                                      const unsigned short* __restrict__ vtb,
                                                      unsigned short* __restrict__ yb) {
  __shared__ unsigned short Ks[64 * 128];     // 16 KB
  __shared__ unsigned short Vt[128 * 64];     // 16 KB
  __shared__ unsigned short Ps[4][32 * 64];   // 16 KB

  const int bx = blockIdx.x;
  const int h = blockIdx.y;
  const int bz = blockIdx.z;
  const int qt = bz ? bx : (15 - bx);     // bz-pairing: CU partner gets 15-qt
  const int tid = threadIdx.x;
  const int wave = tid >> 6, lane = tid & 63;
  const int quad = lane >> 4, l16 = lane & 15;
  const int q0 = qt * 128;
  const int base0 = q0 + wave * 32;       // sg=0 row group
  const int base1 = base0 + 16;           // sg=1 row group
  const int kdiag0 = base0 >> 6, kdiag1 = base1 >> 6;

  const unsigned short* qg = qb + (size_t)(bz * NH + h) * SEQ * HD;
  const unsigned short* kg = kb + (size_t)(bz * NKV + (h >> 2)) * SEQ * HD;
  const unsigned short* vg = vtb + (size_t)(bz * NKV + (h >> 2)) * HD * SEQ;
  unsigned short* psw = &Ps[wave][0];

  bf16x8 qf[2][4];
#pragma unroll
  for (int sg = 0; sg < 2; ++sg)
#pragma unroll
    for (int ds = 0; ds < 4; ++ds)
      qf[sg][ds] = *(const bf16x8*)(qg + (size_t)(base0 + sg * 16 + l16) * HD + ds * 32 + quad * 8);

  f32x4 oacc[2][8];
#pragma unroll
  for (int sg = 0; sg < 2; ++sg)
#pragma unroll
    for (int j = 0; j < 8; ++j) oacc[sg][j] = f32x4{0.f, 0.f, 0.f, 0.f};
  float m_i[2] = {-__builtin_inff(), -__builtin_inff()};
  float l_i[2] = {0.f, 0.f};

  // staging thread mapping
  const int krw = tid >> 4, kgr = tid & 15;   // K: 16 rows/iter, 16 granules/row
  const int vdw = tid >> 3, vgr = tid & 7;    // V: 32 d/iter, 8 granules/row

  const int nkt = 2 * qt + 2;

  u16x8 pk[4], pv[4];
#pragma unroll
  for (int i = 0; i < 4; ++i)
    pk[i] = *(const u16x8*)(kg + (size_t)(i * 16 + krw) * HD + kgr * 8);
#pragma unroll
  for (int i = 0; i < 4; ++i)
    pv[i] = *(const u16x8*)(vg + (size_t)(i * 32 + vdw) * SEQ + vgr * 8);

  for (int kt = 0; kt < nkt; ++kt) {
#pragma unroll
    for (int i = 0; i < 4; ++i) {
      int row = i * 16 + krw;
      *(u16x8*)&Ks[row * 128 + ((kgr ^ (row & 15)) << 3)] = pk[i];
    }
#pragma unroll
    for (int i = 0; i < 4; ++i) {
      int d = i * 32 + vdw;
      *(u16x8*)&Vt[d * 64 + ((vgr ^ (d & 7)) << 3)] = pv[i];
    }
    __syncthreads();

    if (kt + 1 < nkt) {                  // prefetch next tile into regs
#pragma unroll
      for (int i = 0; i < 4; ++i)
        pk[i] = *(const u16x8*)(kg + (size_t)((kt + 1) * 64 + i * 16 + krw) * HD + kgr * 8);
#pragma unroll
      for (int i = 0; i < 4; ++i)
        pv[i] = *(const u16x8*)(vg + (size_t)(i * 32 + vdw) * SEQ + (kt + 1) * 64 + vgr * 8);
    }

    const bool act0 = (kt <= kdiag0);    // act0 implies act1
    if (kt <= kdiag1) {
      // ---- S^T = K * Q^T, K-frags shared across both q-subgroups ----
      f32x4 st[2][4];
#pragma unroll
      for (int sg = 0; sg < 2; ++sg)
#pragma unroll
        for (int mt = 0; mt < 4; ++mt) st[sg][mt] = f32x4{0.f, 0.f, 0.f, 0.f};
#pragma unroll
      for (int mt = 0; mt < 4; ++mt)
#pragma unroll
        for (int ds = 0; ds < 4; ++ds) {
          bf16x8 kf = *(const bf16x8*)&Ks[(mt * 16 + l16) * 128 + ((((ds << 2) + quad) ^ l16) << 3)];
          if (act0)
            st[0][mt] = __builtin_amdgcn_mfma_f32_16x16x32_bf16(kf, qf[0][ds], st[0][mt], 0, 0, 0);
          st[1][mt] = __builtin_amdgcn_mfma_f32_16x16x32_bf16(kf, qf[1][ds], st[1][mt], 0, 0, 0);
        }

      // ---- online softmax per subgroup (all state keyed by l16) ----
#pragma unroll
      for (int sg = 0; sg < 2; ++sg) {
        if (sg == 0 && !act0) continue;
        const int base = sg ? base1 : base0;
        const int qrow = base + l16;
        float p[4][4];
        float mx = -__builtin_inff();
        if (kt == (sg ? kdiag1 : kdiag0)) {    // diagonal tile: causal mask
#pragma unroll
          for (int mt = 0; mt < 4; ++mt)
#pragma unroll
            for (int r = 0; r < 4; ++r) {
              int kp = kt * 64 + mt * 16 + quad * 4 + r;
              float v = (kp <= qrow) ? st[sg][mt][r] : -__builtin_inff();
              p[mt][r] = v;
              mx = fmaxf(mx, v);
            }
        } else {
#pragma unroll
          for (int mt = 0; mt < 4; ++mt)
#pragma unroll
            for (int r = 0; r < 4; ++r) {
              p[mt][r] = st[sg][mt][r];
              mx = fmaxf(mx, st[sg][mt][r]);
            }
        }
        mx = fmaxf(mx, __shfl_xor(mx, 16));
        mx = fmaxf(mx, __shfl_xor(mx, 32));
        float mnew = fmaxf(m_i[sg], mx);
        float rs = 0.f;
#pragma unroll
        for (int mt = 0; mt < 4; ++mt)
#pragma unroll
          for (int r = 0; r < 4; ++r) {
            float e = exp2f(p[mt][r] - mnew);
            p[mt][r] = e;
            rs += e;
          }
        rs += __shfl_xor(rs, 16);
        rs += __shfl_xor(rs, 32);
        if (__any(mnew > m_i[sg])) {          // rescale only when max moved
          float a = exp2f(m_i[sg] - mnew);
#pragma unroll
          for (int j = 0; j < 8; ++j) oacc[sg][j] *= a;
          l_i[sg] = l_i[sg] * a + rs;
        } else {
          l_i[sg] += rs;
        }
        m_i[sg] = mnew;

        // P store: u16x4 at kp = mt*16+quad*4, row rq = sg*16+l16 (swizzled)
        const int rq = sg * 16 + l16;
#pragma unroll
        for (int mt = 0; mt < 4; ++mt) {
          u16x4 w;
#pragma unroll
          for (int r = 0; r < 4; ++r) w[r] = fto16(p[mt][r]);
          int g = mt * 2 + (quad >> 1);
          *(u16x4*)&psw[rq * 64 + ((g ^ (l16 & 7)) << 3) + (quad & 1) * 4] = w;
        }
      }

      __asm__ volatile("s_waitcnt lgkmcnt(0)" ::: "memory");  // own P writes -> reads

      // ---- O^T += V^T * P^T, V-frags shared across both q-subgroups ----
#pragma unroll
      for (int c = 0; c < 2; ++c) {
        bf16x8 pf0, pf1;
        if (act0)
          pf0 = *(const bf16x8*)&psw[l16 * 64 + ((((c << 2) + quad) ^ (l16 & 7)) << 3)];
        pf1 = *(const bf16x8*)&psw[(16 + l16) * 64 + ((((c << 2) + quad) ^ (l16 & 7)) << 3)];
#pragma unroll
        for (int mt = 0; mt < 8; ++mt) {
          bf16x8 vf = *(const bf16x8*)&Vt[(mt * 16 + l16) * 64 + ((((c << 2) + quad) ^ (l16 & 7)) << 3)];
          if (act0)
            oacc[0][mt] = __builtin_amdgcn_mfma_f32_16x16x32_bf16(vf, pf0, oacc[0][mt], 0, 0, 0);
          oacc[1][mt] = __builtin_amdgcn_mfma_f32_16x16x32_bf16(vf, pf1, oacc[1][mt], 0, 0, 0);
        }
      }
    }
    __syncthreads();                     // all LDS reads done before next stores
  }

  // epilogue: O^T row = d = mt*16+quad*4+r, col = q = l16; per-lane invl
#pragma unroll
  for (int sg = 0; sg < 2; ++sg) {
    float il = 1.0f / l_i[sg];
    int qrow = base0 + sg * 16 + l16;
#pragma unroll
    for (int mt = 0; mt < 8; ++mt) {
      u16x4 o;
#pragma unroll
      for (int r = 0; r < 4; ++r) o[r] = fto16(oacc[sg][mt][r] * il);
      *(u16x4*)&yb[(size_t)(bz * SEQ + qrow) * DMODEL + h * HD + mt * 16 + quad * 4] = o;
    }
  }
}

extern "C" void kernel_launch(void* const* d_in, const int* in_sizes, int n_in,
                              void* d_out, int out_size, void* d_ws, size_t ws_size,
                              hipStream_t stream) {
  (void)in_sizes; (void)n_in; (void)out_size; (void)ws_size;
  const float* x  = (const float*)d_in[0];
  const float* Wq = (const float*)d_in[1];
  const float* Wk = (const float*)d_in[2];
  const float* Wv = (const float*)d_in[3];
  const float* Wp = (const float*)d_in[4];
  const float* qg = (const float*)d_in[5];
  float* out = (float*)d_out;
  char* ws = (char*)d_ws;

  // workspace layout; yb aliases xb (x consumed by GEMM1 before attn writes y)
  unsigned short* xb   = (unsigned short*)(ws + 0);          // 16.78 MB
  unsigned short* Wcat = (unsigned short*)(ws + 16777216);   // 12.58 MB (Wq|Wk|Wv rows)
  unsigned short* Wpq  = (unsigned short*)(ws + 29360128);   // 8.39 MB
  unsigned short* qkvb = (unsigned short*)(ws + 37748736);   // 25.17 MB (bf16 qkv)
  unsigned short* qbuf = (unsigned short*)(ws + 62914560);   // 16.78 MB
  unsigned short* kbuf = (unsigned short*)(ws + 79691776);   // 4.19 MB
  unsigned short* vtb  = (unsigned short*)(ws + 83886080);   // 4.19 MB (V^T)
  unsigned short* yb   = xb;

  fq_kernel<<<81920 / 4, 256, 0, stream>>>(Wq, Wk, Wv, Wp, Wcat, Wpq);
  conv_kernel<<<8388608 / 1024, 256, 0, stream>>>(x, xb, 8388608);
  gemm_bt<unsigned short><<<dim3(32, 24), 256, 0, stream>>>(xb, Wcat, qkvb, MROWS, NTOT, DMODEL);
  normrope_kernel<<<MROWS, 256, 0, stream>>>(qkvb, qg, qbuf, kbuf);
  vtrans_kernel<<<dim3(32, 2, 8), 256, 0, stream>>>(qkvb, vtb);
  attn_kernel<<<dim3(16, NH, 2), 256, 0, stream>>>(qbuf, kbuf, vtb, yb);
  gemm_bt<float><<<dim3(32, 16), 256, 0, stream>>>(yb, Wpq, out, MROWS, DMODEL, DMODEL);
}